// Round 1
// baseline (1431.944 us; speedup 1.0000x reference)
//
#include <hip/hip_runtime.h>
#include <math.h>

#define B_   16
#define CI   2048
#define NI   16
#define CJ   64
#define NJ   32
#define JM   2048      // CJ*NJ
#define CH   8         // i's per block
#define ALPHA 8.0f

// ---------------------------------------------------------------------------
// Pass kernel. 512 threads: bh = tid>>8 in {0,1} -> b = bh*8+bb (bb 0..7)
// jg = tid&255 -> jm0 = jg*8 (8 contiguous jm per thread, within one j)
// Each block handles CH=8 consecutive i's, all 16 b, all 2048 jm.
// PASS 0: acc += u  (c == 1)
// PASS 1: a0 = sum_m v0*u (stored), c = softmax(8*a0)*64, acc += c*u
// PASS 2: L = a0 + sum_m v1*u, c = softmax(8*L)*64, acc += c*u
// ---------------------------------------------------------------------------
template <int PASS>
__global__ __launch_bounds__(512, 2)
void pass_kernel(const float* __restrict__ x, const float* __restrict__ w,
                 const float* __restrict__ vprev, float* __restrict__ a0,
                 float* __restrict__ s_out)
{
    __shared__ float xs[CH][B_][NI];   // 8 KB staged inputs
    __shared__ float Ls[B_][CJ];       // 4 KB logits for softmax
    __shared__ float smax[B_], sinv[B_];

    const int tid  = threadIdx.x;
    const int bh   = tid >> 8;        // 0..1
    const int jg   = tid & 255;
    const int jm0  = jg * 8;
    const int jcol = jg >> 2;         // j in 0..63 (4 lanes per j)
    const int i0   = blockIdx.x * CH;

    // stage x[b, i0..i0+7, :] into LDS (each thread: one aligned float4)
    {
        const int f    = tid * 4;
        const int n    = f & 15;
        const int bidx = (f >> 4) & 15;
        const int ci   = f >> 8;
        const float4 xv = *(const float4*)(x + (size_t)bidx * (CI * NI)
                                             + (size_t)(i0 + ci) * NI + n);
        *(float4*)(&xs[ci][bidx][n]) = xv;
    }

    float acc[8][8];
#pragma unroll
    for (int bb = 0; bb < 8; ++bb)
#pragma unroll
        for (int k = 0; k < 8; ++k) acc[bb][k] = 0.0f;

    __syncthreads();

    for (int ci = 0; ci < CH; ++ci) {
        const int i = i0 + ci;

        // ---- recompute u[b, i, jm0..jm0+7] for b = bh*8 .. bh*8+7 ----
        float u[8][8];
#pragma unroll
        for (int bb = 0; bb < 8; ++bb)
#pragma unroll
            for (int k = 0; k < 8; ++k) u[bb][k] = 0.0f;

        const float* wrow = w + (size_t)i * (NI * JM) + jm0;
#pragma unroll
        for (int n = 0; n < NI; ++n) {
            const float4 w0 = *(const float4*)(wrow + (size_t)n * JM);
            const float4 w1 = *(const float4*)(wrow + (size_t)n * JM + 4);
#pragma unroll
            for (int bb = 0; bb < 8; ++bb) {
                const float xv = xs[ci][bh * 8 + bb][n];
                u[bb][0] = fmaf(xv, w0.x, u[bb][0]);
                u[bb][1] = fmaf(xv, w0.y, u[bb][1]);
                u[bb][2] = fmaf(xv, w0.z, u[bb][2]);
                u[bb][3] = fmaf(xv, w0.w, u[bb][3]);
                u[bb][4] = fmaf(xv, w1.x, u[bb][4]);
                u[bb][5] = fmaf(xv, w1.y, u[bb][5]);
                u[bb][6] = fmaf(xv, w1.z, u[bb][6]);
                u[bb][7] = fmaf(xv, w1.w, u[bb][7]);
            }
        }

        if (PASS == 0) {
#pragma unroll
            for (int bb = 0; bb < 8; ++bb)
#pragma unroll
                for (int k = 0; k < 8; ++k) acc[bb][k] += u[bb][k];
        } else {
            // ---- agreement: ap[b,j] = sum_m vprev[b,j,m]*u[b,i,j,m] ----
            float ap[8];
#pragma unroll
            for (int bb = 0; bb < 8; ++bb) {
                const int b = bh * 8 + bb;
                const float4 v0 = *(const float4*)(vprev + b * JM + jm0);
                const float4 v1 = *(const float4*)(vprev + b * JM + jm0 + 4);
                float t = u[bb][0] * v0.x + u[bb][1] * v0.y
                        + u[bb][2] * v0.z + u[bb][3] * v0.w
                        + u[bb][4] * v1.x + u[bb][5] * v1.y
                        + u[bb][6] * v1.z + u[bb][7] * v1.w;
                // 4 lanes share one (b,j): butterfly over the quad
                t += __shfl_xor(t, 1);
                t += __shfl_xor(t, 2);
                ap[bb] = t;
            }

            // logits
            float L[8];
#pragma unroll
            for (int bb = 0; bb < 8; ++bb) {
                if (PASS == 1) {
                    L[bb] = ap[bb];
                } else {
                    const int b = bh * 8 + bb;
                    L[bb] = ap[bb] + a0[((size_t)b * CI + i) * CJ + jcol];
                }
            }
            if ((jg & 3) == 0) {
#pragma unroll
                for (int bb = 0; bb < 8; ++bb) {
                    Ls[bh * 8 + bb][jcol] = L[bb];
                    if (PASS == 1) {
                        const int b = bh * 8 + bb;
                        a0[((size_t)b * CI + i) * CJ + jcol] = ap[bb];
                    }
                }
            }
            __syncthreads();

            // softmax over j (64 values per b); thread -> (rb, rj) handles 2 j's
            {
                const int rb = tid >> 5, rj = tid & 31;
                const float x1 = Ls[rb][rj];
                const float x2 = Ls[rb][rj + 32];
                float mx = fmaxf(x1, x2);
#pragma unroll
                for (int s2 = 1; s2 < 32; s2 <<= 1)
                    mx = fmaxf(mx, __shfl_xor(mx, s2));
                float ex = __expf(ALPHA * (x1 - mx)) + __expf(ALPHA * (x2 - mx));
#pragma unroll
                for (int s2 = 1; s2 < 32; s2 <<= 1)
                    ex += __shfl_xor(ex, s2);
                if (rj == 0) { smax[rb] = mx; sinv[rb] = 64.0f / ex; }
            }
            __syncthreads();

            // c = softmax(8*L)*64 ; acc += c*u
#pragma unroll
            for (int bb = 0; bb < 8; ++bb) {
                const int b = bh * 8 + bb;
                const float c = __expf(ALPHA * (L[bb] - smax[b])) * sinv[b];
#pragma unroll
                for (int k = 0; k < 8; ++k)
                    acc[bb][k] = fmaf(c, u[bb][k], acc[bb][k]);
            }
            // no 3rd barrier needed: next iter's Ls write is fenced by its own
            // first __syncthreads, and smax reads here precede it
        }
    }

    // cross-block reduction into s_out (zeroed by memset)
#pragma unroll
    for (int bb = 0; bb < 8; ++bb) {
        const int b = bh * 8 + bb;
#pragma unroll
        for (int k = 0; k < 8; ++k)
            unsafeAtomicAdd(s_out + b * JM + jm0 + k, acc[bb][k]);
    }
}

// ---------------------------------------------------------------------------
// squash: v = (|s|^2/(1+|s|^2)) * s * rsqrt(|s|^2 + 1e-7), rows of 32 (n_j)
// ---------------------------------------------------------------------------
__global__ __launch_bounds__(256)
void squash_kernel(const float* __restrict__ s, float* __restrict__ v)
{
    const int g = blockIdx.x * 256 + threadIdx.x;   // 0..32767
    const float val = s[g];
    float sq = val * val;
#pragma unroll
    for (int k = 1; k < 32; k <<= 1) sq += __shfl_xor(sq, k);
    v[g] = (sq / (1.0f + sq)) * (val * rsqrtf(sq + 1e-7f));
}

// ---------------------------------------------------------------------------
extern "C" void kernel_launch(void* const* d_in, const int* in_sizes, int n_in,
                              void* d_out, int out_size, void* d_ws, size_t ws_size,
                              hipStream_t stream)
{
    const float* x = (const float*)d_in[0];
    const float* w = (const float*)d_in[1];
    float* out = (float*)d_out;
    float* ws  = (float*)d_ws;

    float* S0 = ws;               // 32768
    float* S1 = ws + 32768;       // 32768
    float* S2 = ws + 65536;       // 32768
    float* V0 = ws + 98304;       // 32768
    float* V1 = ws + 131072;      // 32768
    float* A0 = ws + 163840;      // 16*2048*64 = 2,097,152 floats (8 MB)

    hipMemsetAsync(S0, 0, (size_t)3 * 32768 * sizeof(float), stream);

    pass_kernel<0><<<dim3(256), dim3(512), 0, stream>>>(x, w, nullptr, nullptr, S0);
    squash_kernel<<<dim3(128), dim3(256), 0, stream>>>(S0, V0);
    pass_kernel<1><<<dim3(256), dim3(512), 0, stream>>>(x, w, V0, A0, S1);
    squash_kernel<<<dim3(128), dim3(256), 0, stream>>>(S1, V1);
    pass_kernel<2><<<dim3(256), dim3(512), 0, stream>>>(x, w, V1, A0, S2);
    squash_kernel<<<dim3(128), dim3(256), 0, stream>>>(S2, out);
}

// Round 2
// 767.391 us; speedup vs baseline: 1.8660x; 1.8660x over previous
//
#include <hip/hip_runtime.h>
#include <math.h>

#define B_   16
#define CI   2048
#define NI   16
#define CJ   64
#define NJ   32
#define JM   2048      // CJ*NJ
#define CH   8         // i's per block
#define NBLK 256       // i-chunks = CI/CH
#define ALPHA 8.0f

// ---------------------------------------------------------------------------
// Pass kernel. 1024 threads: bh = tid>>8 in {0..3} -> b = bh*4+bb (bb 0..3)
// jg = tid&255 -> jm0 = jg*8 (8 contiguous jm per thread, quarter of one j)
// Each block handles CH=8 consecutive i's, all 16 b, all 2048 jm.
// Per-thread live state: u[4][8] + acc[4][8] = 64 floats (no spills at 128 VGPR).
// PASS 0: acc += u
// PASS 1: a0 = sum_m v0*u (stored), c = softmax(8*a0)*64, acc += c*u
// PASS 2: L = a0 + sum_m v1*u, c = softmax(8*L)*64, acc += c*u
// ATOMIC=false: write per-block partials (reduced by reduce_squash)
// ATOMIC=true : legacy unsafeAtomicAdd fallback (if ws too small)
// ---------------------------------------------------------------------------
template <int PASS, bool ATOMIC>
__global__ __launch_bounds__(1024, 4)
void pass_kernel(const float* __restrict__ x, const float* __restrict__ w,
                 const float* __restrict__ vprev, float* __restrict__ a0,
                 float* __restrict__ sout)
{
    __shared__ float xs[CH][B_][NI];   // 8 KB staged inputs
    __shared__ float Ls[B_][CJ];       // 4 KB logits for softmax
    __shared__ float smax[B_], sinv[B_];

    const int tid  = threadIdx.x;
    const int bh   = tid >> 8;        // 0..3
    const int jg   = tid & 255;
    const int jm0  = jg * 8;
    const int jcol = jg >> 2;         // j in 0..63 (4 lanes per j)
    const int i0   = blockIdx.x * CH;

    // stage x[b, i0..i0+7, :] into LDS (512 aligned float4 loads)
    if (tid < 512) {
        const int f    = tid * 4;
        const int n    = f & 15;
        const int bidx = (f >> 4) & 15;
        const int ci   = f >> 8;
        *(float4*)(&xs[ci][bidx][n]) =
            *(const float4*)(x + (size_t)bidx * (CI * NI)
                               + (size_t)(i0 + ci) * NI + n);
    }

    float acc[4][8];
#pragma unroll
    for (int bb = 0; bb < 4; ++bb)
#pragma unroll
        for (int k = 0; k < 8; ++k) acc[bb][k] = 0.0f;

    __syncthreads();

    for (int ci = 0; ci < CH; ++ci) {
        const int i = i0 + ci;

        // ---- recompute u[b, i, jm0..jm0+7] for b = bh*4 .. bh*4+3 ----
        float u[4][8];
#pragma unroll
        for (int bb = 0; bb < 4; ++bb)
#pragma unroll
            for (int k = 0; k < 8; ++k) u[bb][k] = 0.0f;

        const float* wrow = w + (size_t)i * (NI * JM) + jm0;
#pragma unroll
        for (int n = 0; n < NI; ++n) {
            const float4 w0 = *(const float4*)(wrow + (size_t)n * JM);
            const float4 w1 = *(const float4*)(wrow + (size_t)n * JM + 4);
#pragma unroll
            for (int bb = 0; bb < 4; ++bb) {
                const float xv = xs[ci][bh * 4 + bb][n];
                u[bb][0] = fmaf(xv, w0.x, u[bb][0]);
                u[bb][1] = fmaf(xv, w0.y, u[bb][1]);
                u[bb][2] = fmaf(xv, w0.z, u[bb][2]);
                u[bb][3] = fmaf(xv, w0.w, u[bb][3]);
                u[bb][4] = fmaf(xv, w1.x, u[bb][4]);
                u[bb][5] = fmaf(xv, w1.y, u[bb][5]);
                u[bb][6] = fmaf(xv, w1.z, u[bb][6]);
                u[bb][7] = fmaf(xv, w1.w, u[bb][7]);
            }
        }

        if (PASS == 0) {
#pragma unroll
            for (int bb = 0; bb < 4; ++bb)
#pragma unroll
                for (int k = 0; k < 8; ++k) acc[bb][k] += u[bb][k];
        } else {
            // ---- agreement: ap[b,j] = sum_m vprev[b,j,m]*u[b,i,j,m] ----
            float ap[4];
#pragma unroll
            for (int bb = 0; bb < 4; ++bb) {
                const int b = bh * 4 + bb;
                const float4 v0 = *(const float4*)(vprev + b * JM + jm0);
                const float4 v1 = *(const float4*)(vprev + b * JM + jm0 + 4);
                float t = u[bb][0] * v0.x + u[bb][1] * v0.y
                        + u[bb][2] * v0.z + u[bb][3] * v0.w
                        + u[bb][4] * v1.x + u[bb][5] * v1.y
                        + u[bb][6] * v1.z + u[bb][7] * v1.w;
                // 4 lanes share one (b,j): butterfly over the quad
                t += __shfl_xor(t, 1);
                t += __shfl_xor(t, 2);
                ap[bb] = t;
            }

            // logits
            float L[4];
#pragma unroll
            for (int bb = 0; bb < 4; ++bb) {
                if (PASS == 1) {
                    L[bb] = ap[bb];
                } else {
                    const int b = bh * 4 + bb;
                    L[bb] = ap[bb] + a0[((size_t)b * CI + i) * CJ + jcol];
                }
            }
            if ((jg & 3) == 0) {
#pragma unroll
                for (int bb = 0; bb < 4; ++bb) {
                    const int b = bh * 4 + bb;
                    Ls[b][jcol] = L[bb];
                    if (PASS == 1)
                        a0[((size_t)b * CI + i) * CJ + jcol] = ap[bb];
                }
            }
            __syncthreads();

            // softmax over j (64 values per b); threads 0..511: (rb, rj)
            if (tid < 512) {
                const int rb = tid >> 5, rj = tid & 31;
                const float x1 = Ls[rb][rj];
                const float x2 = Ls[rb][rj + 32];
                float mx = fmaxf(x1, x2);
#pragma unroll
                for (int s2 = 1; s2 < 32; s2 <<= 1)
                    mx = fmaxf(mx, __shfl_xor(mx, s2));
                float ex = __expf(ALPHA * (x1 - mx)) + __expf(ALPHA * (x2 - mx));
#pragma unroll
                for (int s2 = 1; s2 < 32; s2 <<= 1)
                    ex += __shfl_xor(ex, s2);
                if (rj == 0) { smax[rb] = mx; sinv[rb] = 64.0f / ex; }
            }
            __syncthreads();

            // c = softmax(8*L)*64 ; acc += c*u
#pragma unroll
            for (int bb = 0; bb < 4; ++bb) {
                const int b = bh * 4 + bb;
                const float c = __expf(ALPHA * (L[bb] - smax[b])) * sinv[b];
#pragma unroll
                for (int k = 0; k < 8; ++k)
                    acc[bb][k] = fmaf(c, u[bb][k], acc[bb][k]);
            }
            // barrier safety: next iter's Ls/smax writes are ordered by its own
            // barriers; this iter's reads complete before those barriers pass.
        }
    }

    if (ATOMIC) {
#pragma unroll
        for (int bb = 0; bb < 4; ++bb) {
            const int b = bh * 4 + bb;
#pragma unroll
            for (int k = 0; k < 8; ++k)
                unsafeAtomicAdd(sout + b * JM + jm0 + k, acc[bb][k]);
        }
    } else {
        float* dst = sout + (size_t)blockIdx.x * (B_ * JM);
#pragma unroll
        for (int bb = 0; bb < 4; ++bb) {
            const int b = bh * 4 + bb;
            *(float4*)(dst + b * JM + jm0)     =
                make_float4(acc[bb][0], acc[bb][1], acc[bb][2], acc[bb][3]);
            *(float4*)(dst + b * JM + jm0 + 4) =
                make_float4(acc[bb][4], acc[bb][5], acc[bb][6], acc[bb][7]);
        }
    }
}

// ---------------------------------------------------------------------------
// reduce 256 partials + squash. grid 256 x 128 threads, one output each.
// ---------------------------------------------------------------------------
__global__ __launch_bounds__(128)
void reduce_squash(const float* __restrict__ part, float* __restrict__ v)
{
    const int g = blockIdx.x * 128 + threadIdx.x;   // 0..32767
    float s = 0.0f;
#pragma unroll 8
    for (int p = 0; p < NBLK; ++p)
        s += part[(size_t)p * (B_ * JM) + g];
    float sq = s * s;
#pragma unroll
    for (int k = 1; k < 32; k <<= 1) sq += __shfl_xor(sq, k);
    v[g] = (sq / (1.0f + sq)) * (s * rsqrtf(sq + 1e-7f));
}

// fallback squash (atomic path)
__global__ __launch_bounds__(256)
void squash_kernel(const float* __restrict__ s, float* __restrict__ v)
{
    const int g = blockIdx.x * 256 + threadIdx.x;
    const float val = s[g];
    float sq = val * val;
#pragma unroll
    for (int k = 1; k < 32; k <<= 1) sq += __shfl_xor(sq, k);
    v[g] = (sq / (1.0f + sq)) * (val * rsqrtf(sq + 1e-7f));
}

// ---------------------------------------------------------------------------
extern "C" void kernel_launch(void* const* d_in, const int* in_sizes, int n_in,
                              void* d_out, int out_size, void* d_ws, size_t ws_size,
                              hipStream_t stream)
{
    const float* x = (const float*)d_in[0];
    const float* w = (const float*)d_in[1];
    float* out = (float*)d_out;
    float* ws  = (float*)d_ws;

    float* A0   = ws;                                   // 16*2048*64 = 2,097,152
    float* V0   = A0 + (size_t)B_ * CI * CJ;            // 32768
    float* V1   = V0 + B_ * JM;                         // 32768
    float* PART = V1 + B_ * JM;                         // 256*16*2048 = 8,388,608
    const size_t need_part =
        ((size_t)B_ * CI * CJ + 2 * (size_t)B_ * JM
         + (size_t)NBLK * B_ * JM) * sizeof(float);     // ~42.6 MB

    if (ws_size >= need_part) {
        pass_kernel<0, false><<<NBLK, 1024, 0, stream>>>(x, w, nullptr, nullptr, PART);
        reduce_squash<<<256, 128, 0, stream>>>(PART, V0);
        pass_kernel<1, false><<<NBLK, 1024, 0, stream>>>(x, w, V0, A0, PART);
        reduce_squash<<<256, 128, 0, stream>>>(PART, V1);
        pass_kernel<2, false><<<NBLK, 1024, 0, stream>>>(x, w, V1, A0, PART);
        reduce_squash<<<256, 128, 0, stream>>>(PART, out);
    } else {
        // fallback: atomic accumulation (round-1 behavior, new tiling)
        float* S0 = V1 + B_ * JM;       // 32768
        float* S1 = S0 + B_ * JM;
        float* S2 = S1 + B_ * JM;
        hipMemsetAsync(S0, 0, (size_t)3 * B_ * JM * sizeof(float), stream);
        pass_kernel<0, true><<<NBLK, 1024, 0, stream>>>(x, w, nullptr, nullptr, S0);
        squash_kernel<<<128, 256, 0, stream>>>(S0, V0);
        pass_kernel<1, true><<<NBLK, 1024, 0, stream>>>(x, w, V0, A0, S1);
        squash_kernel<<<128, 256, 0, stream>>>(S1, V1);
        pass_kernel<2, true><<<NBLK, 1024, 0, stream>>>(x, w, V1, A0, S2);
        squash_kernel<<<128, 256, 0, stream>>>(S2, out);
    }
}